// Round 2
// baseline (1216.635 us; speedup 1.0000x reference)
//
#include <hip/hip_runtime.h>

#define N_TOK 16384
#define D 64
#define NC 512
#define KSEL 16
#define NEG_INF -3.0e38f

// ---------------- kernel A: center squared norms ----------------
__global__ void c2_kernel(const float* __restrict__ ctrs, float* __restrict__ c2) {
    int c = blockIdx.x * blockDim.x + threadIdx.x;
    if (c < NC) {
        const float4* row = (const float4*)(ctrs + c * D);
        float s = 0.f;
        #pragma unroll
        for (int i = 0; i < D / 4; ++i) {
            float4 v = row[i];
            s += v.x * v.x + v.y * v.y + v.z * v.z + v.w * v.w;
        }
        c2[c] = s;
    }
}

// ---------------- kernel Z: zero out + hist ----------------
__global__ void zero_kernel(float4* __restrict__ out4, int4* __restrict__ hist4) {
    int i = blockIdx.x * 256 + threadIdx.x;
    out4[i] = make_float4(0.f, 0.f, 0.f, 0.f);
    if (blockIdx.x == 0 && threadIdx.x < NC / 4) hist4[threadIdx.x] = make_int4(0, 0, 0, 0);
}

// ---------------- kernel B: one wave per token — dist + top-16 + softmax ----------------
// Block: 1024 threads = 16 waves, 64 tokens/block (4 per wave).
// s[n,c] = 2*x.c - ||c||^2 (x^2 shift cancels in top-k order and softmax).
// ctrsT[g][c] staged in LDS in two 256-center phases (64KB).
__global__ __launch_bounds__(1024) void topk2_kernel(
    const float* __restrict__ x, const float* __restrict__ ctrs,
    const float* __restrict__ c2, float* __restrict__ scores,
    int* __restrict__ sidx, int* __restrict__ hist) {
    __shared__ float ctrsT[D * 256];   // [g][c] for current 256-center phase

    const int t = threadIdx.x;
    const int lane = t & 63;
    const int wi = t >> 6;                 // 0..15
    const int base = blockIdx.x * 64;
    const int n0 = base + wi * 4;

    // x rows for this wave's 4 tokens (pre-doubled: s = (2x).c - c2, exact)
    float xv0 = 2.f * x[(n0 + 0) * D + lane];
    float xv1 = 2.f * x[(n0 + 1) * D + lane];
    float xv2 = 2.f * x[(n0 + 2) * D + lane];
    float xv3 = 2.f * x[(n0 + 3) * D + lane];

    float st[4][8];   // [token][slot]: slot = phase*4 + j, center = phase*256 + lane*4 + j

    for (int ph = 0; ph < 2; ++ph) {
        __syncthreads();
        // stage 256 centers transposed: conflict-free LDS writes (c contiguous per thread)
        #pragma unroll
        for (int i = 0; i < 4; ++i) {
            int e = t + 1024 * i;          // 0..4095 float4 units
            int c = e & 255, j = e >> 8;   // j = float4 index within row (0..15)
            float4 v = *(const float4*)(ctrs + (ph * 256 + c) * D + j * 4);
            ctrsT[(4 * j + 0) * 256 + c] = v.x;
            ctrsT[(4 * j + 1) * 256 + c] = v.y;
            ctrsT[(4 * j + 2) * 256 + c] = v.z;
            ctrsT[(4 * j + 3) * 256 + c] = v.w;
        }
        __syncthreads();

        float4 c2v = *(const float4*)(c2 + ph * 256 + lane * 4);
        float a0[4], a1[4], a2[4], a3[4];  // a<p>[j]
        #pragma unroll
        for (int j = 0; j < 4; ++j) { }
        a0[0] = -c2v.x; a0[1] = -c2v.y; a0[2] = -c2v.z; a0[3] = -c2v.w;
        a1[0] = -c2v.x; a1[1] = -c2v.y; a1[2] = -c2v.z; a1[3] = -c2v.w;
        a2[0] = -c2v.x; a2[1] = -c2v.y; a2[2] = -c2v.z; a2[3] = -c2v.w;
        a3[0] = -c2v.x; a3[1] = -c2v.y; a3[2] = -c2v.z; a3[3] = -c2v.w;

        #pragma unroll
        for (int g = 0; g < D; ++g) {
            float4 w = *(const float4*)(ctrsT + g * 256 + lane * 4);
            float xg0 = __shfl(xv0, g, 64);
            float xg1 = __shfl(xv1, g, 64);
            float xg2 = __shfl(xv2, g, 64);
            float xg3 = __shfl(xv3, g, 64);
            a0[0] = fmaf(xg0, w.x, a0[0]); a0[1] = fmaf(xg0, w.y, a0[1]);
            a0[2] = fmaf(xg0, w.z, a0[2]); a0[3] = fmaf(xg0, w.w, a0[3]);
            a1[0] = fmaf(xg1, w.x, a1[0]); a1[1] = fmaf(xg1, w.y, a1[1]);
            a1[2] = fmaf(xg1, w.z, a1[2]); a1[3] = fmaf(xg1, w.w, a1[3]);
            a2[0] = fmaf(xg2, w.x, a2[0]); a2[1] = fmaf(xg2, w.y, a2[1]);
            a2[2] = fmaf(xg2, w.z, a2[2]); a2[3] = fmaf(xg2, w.w, a2[3]);
            a3[0] = fmaf(xg3, w.x, a3[0]); a3[1] = fmaf(xg3, w.y, a3[1]);
            a3[2] = fmaf(xg3, w.z, a3[2]); a3[3] = fmaf(xg3, w.w, a3[3]);
        }
        #pragma unroll
        for (int j = 0; j < 4; ++j) {
            st[0][ph * 4 + j] = a0[j];
            st[1][ph * 4 + j] = a1[j];
            st[2][ph * 4 + j] = a2[j];
            st[3][ph * 4 + j] = a3[j];
        }
    }

    // selection + softmax, one token at a time (whole wave cooperates)
    for (int p = 0; p < 4; ++p) {
        float v[8]; int cid[8];
        #pragma unroll
        for (int j = 0; j < 8; ++j) {
            v[j] = st[p][j];
            cid[j] = (j >> 2) * 256 + lane * 4 + (j & 3);
        }
        float res_v = NEG_INF; int res_i = 0;
        for (int r = 0; r < KSEL; ++r) {
            float lm = v[0]; int li = cid[0];
            #pragma unroll
            for (int j = 1; j < 8; ++j) {
                bool b = v[j] > lm;
                lm = b ? v[j] : lm;
                li = b ? cid[j] : li;
            }
            #pragma unroll
            for (int o = 32; o > 0; o >>= 1) {
                float ov = __shfl_xor(lm, o, 64);
                int   oi = __shfl_xor(li, o, 64);
                bool b = (ov > lm) || (ov == lm && oi < li);
                lm = b ? ov : lm;
                li = b ? oi : li;
            }
            if (lane == r) { res_v = lm; res_i = li; }
            #pragma unroll
            for (int j = 0; j < 8; ++j) if (cid[j] == li) v[j] = NEG_INF;
        }
        float m = __shfl(res_v, 0, 64);
        float e = __expf(res_v - m);          // lanes>=16: exp(-huge)=0
        e = (lane < KSEL) ? e : 0.f;
        float sum = e;
        #pragma unroll
        for (int o = 32; o > 0; o >>= 1) sum += __shfl_xor(sum, o, 64);
        float invs = 1.f / sum;
        if (lane < KSEL) {
            int n = n0 + p;
            scores[n * KSEL + lane] = e * invs;
            sidx[n * KSEL + lane] = res_i;
            atomicAdd(&hist[res_i], 1);
        }
    }
}

// ---------------- kernel S: prefix scan of hist (single block) ----------------
__global__ __launch_bounds__(512) void scan_kernel(const int* __restrict__ hist,
                                                   int* __restrict__ offs,
                                                   int* __restrict__ cursor) {
    __shared__ int buf[2][NC];
    int t = threadIdx.x;
    int self = hist[t];
    buf[0][t] = self;
    __syncthreads();
    int a = 0;
    for (int d = 1; d < NC; d <<= 1) {
        int val = buf[a][t] + (t >= d ? buf[a][t - d] : 0);
        buf[1 - a][t] = val;
        __syncthreads();
        a = 1 - a;
    }
    int incl = buf[a][t];
    int excl = incl - self;
    offs[t] = excl;
    cursor[t] = excl;
    if (t == NC - 1) offs[NC] = incl;
}

// ---------------- kernel P: scatter pairs into center-sorted order ----------------
__global__ void scatter_kernel(const int* __restrict__ sidx, const float* __restrict__ scores,
                               int* __restrict__ cursor, int* __restrict__ tokentab,
                               float* __restrict__ scotab) {
    int e = blockIdx.x * 256 + threadIdx.x;   // 0..262143
    int c = sidx[e];
    int pos = atomicAdd(&cursor[c], 1);
    tokentab[pos] = e >> 4;
    scotab[pos] = scores[e];
}

// ---------------- kernel C: center-grouped affine mixing ----------------
// 2 blocks per center; Wv[c] staged in LDS once; scatter-add to out.
__global__ __launch_bounds__(256) void mix2_kernel(
    const float* __restrict__ x, const float* __restrict__ Wv,
    const float* __restrict__ Ov, const int* __restrict__ offs,
    const int* __restrict__ tokentab, const float* __restrict__ scotab,
    float* __restrict__ out) {
    __shared__ float Ws[D * D];
    const int c = blockIdx.x >> 1;
    const int part = ((blockIdx.x & 1) << 2) | (threadIdx.x >> 6);  // 0..7
    const int lane = threadIdx.x & 63;

    #pragma unroll
    for (int i = 0; i < 4; ++i)
        *(float4*)(Ws + (threadIdx.x + 256 * i) * 4) =
            *(const float4*)(Wv + c * (D * D) + (threadIdx.x + 256 * i) * 4);
    float ovl = Ov[c * D + lane];
    __syncthreads();

    const int s1 = offs[c + 1];
    for (int i = offs[c] + part; i < s1; i += 8) {
        int n = tokentab[i];
        float sc = scotab[i];
        float xl = x[n * D + lane];
        float acc = 0.f;
        #pragma unroll
        for (int g = 0; g < D; ++g)
            acc = fmaf(__shfl(xl, g, 64), Ws[g * D + lane], acc);
        unsafeAtomicAdd(out + n * D + lane, sc * (acc + ovl));
    }
}

extern "C" void kernel_launch(void* const* d_in, const int* in_sizes, int n_in,
                              void* d_out, int out_size, void* d_ws, size_t ws_size,
                              hipStream_t stream) {
    const float* x    = (const float*)d_in[0];
    const float* ctrs = (const float*)d_in[1];
    const float* Wv   = (const float*)d_in[2];
    const float* Ov   = (const float*)d_in[3];
    float* out = (float*)d_out;

    float* c2       = (float*)d_ws;                    // 512
    int*   hist     = (int*)d_ws + 512;                // 512
    int*   offs     = (int*)d_ws + 1024;               // 513 (reserve 1024)
    int*   cursor   = (int*)d_ws + 2048;               // 512 (reserve 512)
    float* scores   = (float*)d_ws + 2560;             // 262144
    int*   sidx     = (int*)d_ws + 2560 + 262144;      // 262144
    int*   tokentab = (int*)d_ws + 2560 + 2 * 262144;  // 262144
    float* scotab   = (float*)d_ws + 2560 + 3 * 262144;// 262144

    hipLaunchKernelGGL(zero_kernel, dim3(1024), dim3(256), 0, stream,
                       (float4*)out, (int4*)hist);
    hipLaunchKernelGGL(c2_kernel, dim3(2), dim3(256), 0, stream, ctrs, c2);
    hipLaunchKernelGGL(topk2_kernel, dim3(N_TOK / 64), dim3(1024), 0, stream,
                       x, ctrs, c2, scores, sidx, hist);
    hipLaunchKernelGGL(scan_kernel, dim3(1), dim3(512), 0, stream, hist, offs, cursor);
    hipLaunchKernelGGL(scatter_kernel, dim3(N_TOK * KSEL / 256), dim3(256), 0, stream,
                       sidx, scores, cursor, tokentab, scotab);
    hipLaunchKernelGGL(mix2_kernel, dim3(2 * NC), dim3(256), 0, stream,
                       x, Wv, Ov, offs, tokentab, scotab, out);
}

// Round 3
// 263.515 us; speedup vs baseline: 4.6169x; 4.6169x over previous
//
#include <hip/hip_runtime.h>

#define N_TOK 16384
#define D 64
#define NC 512
#define KSEL 16
#define CPH 128          // centers per LDS phase in topk3
#define CSTR 68          // padded row stride (floats): 272B, 16B-aligned, conflict-free b128

// ---------------- kernel A: center squared norms ----------------
__global__ void c2_kernel(const float* __restrict__ ctrs, float* __restrict__ c2) {
    int c = blockIdx.x * blockDim.x + threadIdx.x;
    if (c < NC) {
        const float4* row = (const float4*)(ctrs + c * D);
        float s = 0.f;
        #pragma unroll
        for (int i = 0; i < D / 4; ++i) {
            float4 v = row[i];
            s += v.x * v.x + v.y * v.y + v.z * v.z + v.w * v.w;
        }
        c2[c] = s;
    }
}

// ---------------- kernel Z: zero out + hist ----------------
__global__ void zero_kernel(float4* __restrict__ out4, int4* __restrict__ hist4) {
    int i = blockIdx.x * 256 + threadIdx.x;
    out4[i] = make_float4(0.f, 0.f, 0.f, 0.f);
    if (blockIdx.x == 0 && threadIdx.x < NC / 4) hist4[threadIdx.x] = make_int4(0, 0, 0, 0);
}

__device__ __forceinline__ unsigned fkey(float f) {
    unsigned u = __float_as_uint(f);
    return (u & 0x80000000u) ? ~u : (u | 0x80000000u);
}
__device__ __forceinline__ float funkey(unsigned k) {
    unsigned u = (k & 0x80000000u) ? (k & 0x7fffffffu) : ~k;
    return __uint_as_float(u);
}

// ---------------- kernel B: dist + top-16 + softmax ----------------
// 1024 threads = 16 waves; 64 tokens/block (4/wave); 256 blocks (1/CU).
// s[n,c] = 2*x.c - ||c||^2 (x^2 shift cancels in top-k order and softmax).
__global__ __launch_bounds__(1024) void topk3_kernel(
    const float* __restrict__ x, const float* __restrict__ ctrs,
    const float* __restrict__ c2, float* __restrict__ scores,
    int* __restrict__ sidx, int* __restrict__ hist) {
    __shared__ float xs[64 * 64];        // 16 KB, token rows (broadcast reads)
    __shared__ float cS[CPH * CSTR];     // 34.8 KB, padded center rows
    __shared__ int lhist[NC];

    const int t = threadIdx.x;
    const int lane = t & 63;
    const int wi = t >> 6;
    const int n0 = blockIdx.x * 64 + wi * 4;

    if (t < NC) lhist[t] = 0;
    // stage x tile (row-major; reads are same-address broadcasts)
    {
        const float4* x4 = (const float4*)(x + blockIdx.x * 64 * D);
        *(float4*)(xs + t * 4) = x4[t];
    }

    float acc[4][8];
    #pragma unroll
    for (int p = 0; p < 4; ++p)
        #pragma unroll
        for (int j = 0; j < 8; ++j) acc[p][j] = 0.f;

    #pragma unroll
    for (int ph = 0; ph < 4; ++ph) {
        __syncthreads();
        // stage 128 centers: coalesced global read, conflict-free b128 LDS write
        #pragma unroll
        for (int i = 0; i < 2; ++i) {
            int e = t + 1024 * i;            // 0..2047 float4 units
            int c = e >> 4, j = e & 15;
            float4 v = *(const float4*)(ctrs + (ph * CPH + c) * D + j * 4);
            *(float4*)(cS + c * CSTR + j * 4) = v;
        }
        __syncthreads();

        #pragma unroll
        for (int gs = 0; gs < 16; ++gs) {
            float4 xv[4];
            #pragma unroll
            for (int p = 0; p < 4; ++p)
                xv[p] = *(const float4*)(xs + (wi * 4 + p) * D + gs * 4);
            #pragma unroll
            for (int jj = 0; jj < 2; ++jj) {
                float4 wv = *(const float4*)(cS + (jj * 64 + lane) * CSTR + gs * 4);
                #pragma unroll
                for (int p = 0; p < 4; ++p) {
                    float a = acc[p][ph * 2 + jj];
                    a = fmaf(xv[p].x, wv.x, a);
                    a = fmaf(xv[p].y, wv.y, a);
                    a = fmaf(xv[p].z, wv.z, a);
                    a = fmaf(xv[p].w, wv.w, a);
                    acc[p][ph * 2 + jj] = a;
                }
            }
        }
    }

    // convert scores to monotone uint keys: s = 2*acc - c2[c]
    unsigned k[4][8];
    #pragma unroll
    for (int s8 = 0; s8 < 8; ++s8) {
        int c = (s8 >> 1) * CPH + (s8 & 1) * 64 + lane;
        float c2v = c2[c];
        #pragma unroll
        for (int p = 0; p < 4; ++p)
            k[p][s8] = fkey(fmaf(2.f, acc[p][s8], -c2v));
    }

    // 16 extract-max rounds, 4 tokens interleaved
    unsigned wk[4] = {0u, 0u, 0u, 0u};
    int wid[4] = {0, 0, 0, 0};
    for (int r = 0; r < KSEL; ++r) {
        unsigned w[4];
        #pragma unroll
        for (int p = 0; p < 4; ++p) {
            unsigned mm = k[p][0];
            #pragma unroll
            for (int j = 1; j < 8; ++j) mm = mm > k[p][j] ? mm : k[p][j];
            w[p] = mm;
        }
        #pragma unroll
        for (int o = 32; o > 0; o >>= 1)
            #pragma unroll
            for (int p = 0; p < 4; ++p) {
                unsigned ov = (unsigned)__shfl_xor((int)w[p], o, 64);
                w[p] = w[p] > ov ? w[p] : ov;
            }
        #pragma unroll
        for (int p = 0; p < 4; ++p) {
            int jj = -1;
            #pragma unroll
            for (int j = 0; j < 8; ++j) jj = (k[p][j] == w[p]) ? j : jj;
            unsigned long long mask = __ballot(jj >= 0);
            int src = __ffsll(mask) - 1;
            int jc = jj & 7;
            int cand = (jc >> 1) * CPH + (jc & 1) * 64 + lane;
            int widx = __shfl(cand, src, 64);
            if (lane == src) k[p][jj] = 0u;        // kill exactly one copy
            if (lane == r) { wk[p] = w[p]; wid[p] = widx; }
        }
    }

    // softmax over selected (lane r holds round-r winner; lane 0 = max)
    #pragma unroll
    for (int p = 0; p < 4; ++p) {
        float val = funkey(wk[p]);
        float mx = __shfl(val, 0, 64);
        float e = (lane < KSEL) ? __expf(val - mx) : 0.f;
        float s = e;
        #pragma unroll
        for (int o = 32; o > 0; o >>= 1) s += __shfl_xor(s, o, 64);
        float inv = 1.f / s;
        if (lane < KSEL) {
            int n = n0 + p;
            scores[n * KSEL + lane] = e * inv;
            sidx[n * KSEL + lane] = wid[p];
            atomicAdd(&lhist[wid[p]], 1);
        }
    }

    __syncthreads();
    if (t < NC) { int h = lhist[t]; if (h) atomicAdd(&hist[t], h); }
}

// ---------------- kernel S: prefix scan of hist (single block) ----------------
__global__ __launch_bounds__(512) void scan_kernel(const int* __restrict__ hist,
                                                   int* __restrict__ offs,
                                                   int* __restrict__ cursor) {
    __shared__ int buf[2][NC];
    int t = threadIdx.x;
    int self = hist[t];
    buf[0][t] = self;
    __syncthreads();
    int a = 0;
    for (int d = 1; d < NC; d <<= 1) {
        int val = buf[a][t] + (t >= d ? buf[a][t - d] : 0);
        buf[1 - a][t] = val;
        __syncthreads();
        a = 1 - a;
    }
    int incl = buf[a][t];
    int excl = incl - self;
    offs[t] = excl;
    cursor[t] = excl;
    if (t == NC - 1) offs[NC] = incl;
}

// ---------------- kernel P: counting-sort scatter with LDS aggregation ----------------
// 64 blocks x 4096 entries. One global atomic per (block,center) only.
__global__ __launch_bounds__(256) void scatter3_kernel(
    const int* __restrict__ sidx, const float* __restrict__ scores,
    int* __restrict__ cursor, int* __restrict__ tokentab,
    float* __restrict__ scotab) {
    __shared__ int lh[NC];
    __shared__ int lbase[NC];
    const int t = threadIdx.x;
    for (int i = t; i < NC; i += 256) lh[i] = 0;
    __syncthreads();
    const int base_e = blockIdx.x * 4096;
    int myc[16];
    #pragma unroll
    for (int i = 0; i < 16; ++i) {
        int e = base_e + t + 256 * i;
        int c = sidx[e];
        myc[i] = c;
        atomicAdd(&lh[c], 1);
    }
    __syncthreads();
    for (int i = t; i < NC; i += 256) {
        int h = lh[i];
        lbase[i] = h ? atomicAdd(&cursor[i], h) : 0;
        lh[i] = 0;
    }
    __syncthreads();
    #pragma unroll
    for (int i = 0; i < 16; ++i) {
        int e = base_e + t + 256 * i;
        int c = myc[i];
        int pos = lbase[c] + atomicAdd(&lh[c], 1);
        tokentab[pos] = (c << 16) | (e >> 4);   // pack center + token
        scotab[pos] = scores[e];
    }
}

// ---------------- kernel C: chunk-balanced affine mixing ----------------
// One wave per 64 consecutive sorted pairs. W[.][lane] in 64 VGPRs; token/score
// made wave-uniform via readfirstlane so x rows come in as scalar loads.
__global__ void mix3_kernel(
    const float* __restrict__ x, const float* __restrict__ Wv,
    const float* __restrict__ Ov, const int* __restrict__ tokentab,
    const float* __restrict__ scotab, float* __restrict__ out) {
    const int lane = threadIdx.x & 63;
    const int gw = blockIdx.x * 4 + (threadIdx.x >> 6);   // 0..4095
    const int i0 = gw * 64;

    float w[D];
    float ovl = 0.f;
    int cur = -1;

    for (int i = i0; i < i0 + 64; ++i) {
        int word = __builtin_amdgcn_readfirstlane(tokentab[i]);
        int c = word >> 16;
        int n = word & 0xffff;
        float sc = __uint_as_float(
            (unsigned)__builtin_amdgcn_readfirstlane((int)__float_as_uint(scotab[i])));
        if (c != cur) {                       // wave-uniform branch
            cur = c;
            #pragma unroll
            for (int g = 0; g < D; ++g) w[g] = Wv[c * (D * D) + g * D + lane];
            ovl = Ov[c * D + lane];
        }
        const float4* xr = (const float4*)(x + n * D);    // uniform -> scalar loads
        float a = 0.f;
        #pragma unroll
        for (int j = 0; j < 16; ++j) {
            float4 xv = xr[j];
            a = fmaf(xv.x, w[4 * j + 0], a);
            a = fmaf(xv.y, w[4 * j + 1], a);
            a = fmaf(xv.z, w[4 * j + 2], a);
            a = fmaf(xv.w, w[4 * j + 3], a);
        }
        unsafeAtomicAdd(out + n * D + lane, sc * (a + ovl));
    }
}

extern "C" void kernel_launch(void* const* d_in, const int* in_sizes, int n_in,
                              void* d_out, int out_size, void* d_ws, size_t ws_size,
                              hipStream_t stream) {
    const float* x    = (const float*)d_in[0];
    const float* ctrs = (const float*)d_in[1];
    const float* Wv   = (const float*)d_in[2];
    const float* Ov   = (const float*)d_in[3];
    float* out = (float*)d_out;

    float* c2       = (float*)d_ws;                    // 512
    int*   hist     = (int*)d_ws + 512;                // 512
    int*   offs     = (int*)d_ws + 1024;               // 513 (reserve 1024)
    int*   cursor   = (int*)d_ws + 2048;               // 512 (reserve 512)
    float* scores   = (float*)d_ws + 2560;             // 262144
    int*   sidx     = (int*)d_ws + 2560 + 262144;      // 262144
    int*   tokentab = (int*)d_ws + 2560 + 2 * 262144;  // 262144
    float* scotab   = (float*)d_ws + 2560 + 3 * 262144;// 262144

    hipLaunchKernelGGL(zero_kernel, dim3(1024), dim3(256), 0, stream,
                       (float4*)out, (int4*)hist);
    hipLaunchKernelGGL(c2_kernel, dim3(2), dim3(256), 0, stream, ctrs, c2);
    hipLaunchKernelGGL(topk3_kernel, dim3(N_TOK / 64), dim3(1024), 0, stream,
                       x, ctrs, c2, scores, sidx, hist);
    hipLaunchKernelGGL(scan_kernel, dim3(1), dim3(512), 0, stream, hist, offs, cursor);
    hipLaunchKernelGGL(scatter3_kernel, dim3(64), dim3(256), 0, stream,
                       sidx, scores, cursor, tokentab, scotab);
    hipLaunchKernelGGL(mix3_kernel, dim3(1024), dim3(256), 0, stream,
                       x, Wv, Ov, tokentab, scotab, out);
}